// Round 11
// baseline (1668.936 us; speedup 1.0000x reference)
//
#include <hip/hip_runtime.h>
#include <hip/hip_bf16.h>
#include <stdint.h>

// MoE: T=8192, D=1024, H=4096, E=16, top-2. Sparse dispatch + bf16 MFMA GEMMs.
// GEMM core: 128x128 tiles, 256 thr (4 waves), BK=32 ring-2 LDS (32 KB) ->
// 5 blocks/CU = 5 independent staging streams per CU (R9/R10 finding: rate
// scales with blocks/CU). Packed 128B-row LDS + XOR involution (0 conflicts,
// proven R10). Min-sync loop. nt-major XCD-chunked tile order.

#define Tn 8192
#define Dn 1024
#define Hn 4096
#define En 16

typedef __attribute__((ext_vector_type(8))) short bf16x8;
typedef __attribute__((ext_vector_type(4))) float f32x4;

__device__ __forceinline__ unsigned short f2bf(float f) {
    union { __hip_bfloat16 h; unsigned short u; } cv;
    cv.h = __float2bfloat16(f);
    return cv.u;
}
__device__ __forceinline__ float bf2f(unsigned short u) {
    union { unsigned int i; float f; } cv;
    cv.i = ((unsigned int)u) << 16;
    return cv.f;
}

__device__ __forceinline__ void gload_lds16(const void* gptr, void* lptr) {
    __builtin_amdgcn_global_load_lds(
        (const __attribute__((address_space(1))) uint32_t*)gptr,
        (__attribute__((address_space(3))) uint32_t*)lptr, 16, 0, 0);
}

// bijective XCD-chunked swizzle (m204)
__device__ __forceinline__ int swz_tile(int v, int total) {
    int q = total >> 3, r = total & 7;
    int x = v & 7, k = v >> 3;
    int b = (x < r) ? x * (q + 1) : r * (q + 1) + (x - r) * q;
    return b + k;
}

// e = #{i in [1,En) : mb[i] <= gm}
__device__ __forceinline__ int find_e(const int* __restrict__ mb, int gm) {
    int e = 0;
#pragma unroll
    for (int i = 1; i < En; i++) e += (mb[i] <= gm) ? 1 : 0;
    return e;
}

__device__ __forceinline__ void waitvm0()  { asm volatile("s_waitcnt vmcnt(0)" ::: "memory"); }
__device__ __forceinline__ void barrier_raw() { asm volatile("s_barrier" ::: "memory"); }

__device__ __forceinline__ bool better(float va, int ia, float vb, int ib) {
    return (va > vb) || (va == vb && ia < ib);
}

// ---------------- gate: 16 tokens/block, Wg in LDS, shuffle top-2 -----------
__global__ __launch_bounds__(256) void gate_kernel(
    const float* __restrict__ x, const float* __restrict__ Wg,
    const float* __restrict__ bg,
    int* cnt, int* tok_e, int* tok_pos, float* tok_w)
{
    __shared__ float wgt[16 * 1028];
    int tid = threadIdx.x;
    int t0 = blockIdx.x * 16;

#pragma unroll
    for (int i = 0; i < 64; i++) {
        int idx = i * 256 + tid;
        int k = idx >> 4, e = idx & 15;
        wgt[e * 1028 + k] = Wg[idx];
    }
    __syncthreads();

    int tok = tid >> 4, e = tid & 15;
    const float4* xr = reinterpret_cast<const float4*>(x + (size_t)(t0 + tok) * Dn);
    const float4* wr = reinterpret_cast<const float4*>(&wgt[e * 1028]);
    float acc = 0.f;
#pragma unroll 8
    for (int q = 0; q < 256; q++) {
        float4 xv = xr[q], wv = wr[q];
        acc += xv.x * wv.x + xv.y * wv.y + xv.z * wv.z + xv.w * wv.w;
    }
    acc += bg[e];

    float v0 = acc, v1 = -1e30f;
    int i0 = e, i1 = -1;
#pragma unroll
    for (int m = 1; m < 16; m <<= 1) {
        float ov0 = __shfl_xor(v0, m, 16); int oi0 = __shfl_xor(i0, m, 16);
        float ov1 = __shfl_xor(v1, m, 16); int oi1 = __shfl_xor(i1, m, 16);
        if (better(ov0, oi0, v0, i0)) {
            if (better(v0, i0, ov1, oi1)) { v1 = v0; i1 = i0; }
            else                          { v1 = ov1; i1 = oi1; }
            v0 = ov0; i0 = oi0;
        } else if (better(ov0, oi0, v1, i1)) {
            v1 = ov0; i1 = oi0;
        }
    }
    if (e == 0) {
        float ex = __expf(v1 - v0);
        float w0 = 1.f / (1.f + ex);
        float w1 = ex / (1.f + ex);
        int p0 = atomicAdd(&cnt[i0], 1);
        int p1 = atomicAdd(&cnt[i1], 1);
        int t = t0 + tok;
        tok_e[t * 2 + 0] = i0; tok_e[t * 2 + 1] = i1;
        tok_pos[t * 2 + 0] = p0; tok_pos[t * 2 + 1] = p1;
        tok_w[t * 2 + 0] = w0; tok_w[t * 2 + 1] = w1;
    }
}

// ---------------- scan: row bases + cumulative 128-row mtiles ---------------
__global__ void scan_kernel(const int* cnt, int* base, int* mb)
{
    if (threadIdx.x == 0 && blockIdx.x == 0) {
        int b = 0, m = 0;
        for (int e = 0; e < En; e++) {
            base[e] = b; mb[e] = m;
            b += cnt[e];
            m += (cnt[e] + 127) >> 7;
        }
        base[En] = b; mb[En] = m;
    }
}

// ---------------- gather ----------------------------------------------------
__global__ __launch_bounds__(256) void gather_kernel(
    const float* __restrict__ x, const int* tok_e, const int* tok_pos,
    const int* base, unsigned short* xg)
{
    int t = blockIdx.x; int tid = threadIdx.x;
    int e0 = tok_e[2 * t], e1 = tok_e[2 * t + 1];
    int r0 = base[e0] + tok_pos[2 * t];
    int r1 = base[e1] + tok_pos[2 * t + 1];
    float4 v = *reinterpret_cast<const float4*>(x + (size_t)t * Dn + tid * 4);
    ushort4 u;
    u.x = f2bf(v.x); u.y = f2bf(v.y); u.z = f2bf(v.z); u.w = f2bf(v.w);
    *reinterpret_cast<ushort4*>(xg + (size_t)r0 * Dn + tid * 4) = u;
    *reinterpret_cast<ushort4*>(xg + (size_t)r1 * Dn + tid * 4) = u;
}

// ---------------- convT: [R][C] f32 -> [C][R] bf16, 64x64 tiles -------------
__global__ __launch_bounds__(512) void convT_kernel(
    const float* __restrict__ src, unsigned short* __restrict__ dst, int R, int C)
{
    int e = blockIdx.z;
    const float* s = src + (size_t)e * R * C;
    unsigned short* d = dst + (size_t)e * R * C;
    __shared__ float tile[64][65];
    int r0 = blockIdx.y * 64, c0 = blockIdx.x * 64;
    int tr = threadIdx.x >> 4;
    int tc4 = (threadIdx.x & 15) * 4;
    float4 v0 = *reinterpret_cast<const float4*>(s + (size_t)(r0 + tr) * C + c0 + tc4);
    float4 v1 = *reinterpret_cast<const float4*>(s + (size_t)(r0 + tr + 32) * C + c0 + tc4);
    tile[tr][tc4 + 0] = v0.x; tile[tr][tc4 + 1] = v0.y;
    tile[tr][tc4 + 2] = v0.z; tile[tr][tc4 + 3] = v0.w;
    tile[tr + 32][tc4 + 0] = v1.x; tile[tr + 32][tc4 + 1] = v1.y;
    tile[tr + 32][tc4 + 2] = v1.z; tile[tr + 32][tc4 + 3] = v1.w;
    __syncthreads();
    ushort4 u0, u1;
    u0.x = f2bf(tile[tc4 + 0][tr]);      u1.x = f2bf(tile[tc4 + 0][tr + 32]);
    u0.y = f2bf(tile[tc4 + 1][tr]);      u1.y = f2bf(tile[tc4 + 1][tr + 32]);
    u0.z = f2bf(tile[tc4 + 2][tr]);      u1.z = f2bf(tile[tc4 + 2][tr + 32]);
    u0.w = f2bf(tile[tc4 + 3][tr]);      u1.w = f2bf(tile[tc4 + 3][tr + 32]);
    *reinterpret_cast<ushort4*>(d + (size_t)(c0 + tr) * R + r0 + tc4) = u0;
    *reinterpret_cast<ushort4*>(d + (size_t)(c0 + tr + 32) * R + r0 + tc4) = u1;
}

// ---------------- 128x128 GEMM, 4 waves, BK=32 ring-2, 5 blocks/CU ----------
// Packed LDS: tile 128 rows x 32 k -> ldsrow = row>>1 (64 x 128B rows),
// chunk ch = ((row&1)<<2 | k/8) ^ (ldsrow&7)  [involution both sides -> 0
// conflicts, proven R10]. Min-sync: 1 vmcnt(0) + 1 barrier per subtile.
// nt-major inside XCD chunk (B panel L2-shared). G1: relu->bf16. G2: bf16 y.
template<bool G1>
__global__ __launch_bounds__(256, 5) void gemm128_kernel(
    const unsigned short* __restrict__ Ag, const unsigned short* __restrict__ Bg,
    const float* __restrict__ bias, unsigned short* __restrict__ outb,
    const int* __restrict__ cnt, const int* __restrict__ base,
    const int* __restrict__ mb)
{
    constexpr int KDIM = G1 ? Dn : Hn;
    constexpr int NOUT = G1 ? Hn : Dn;
    constexpr int NTN = NOUT / 128;        // n-tiles
    constexpr int NT = KDIM / 32;          // K sub-tiles
    __shared__ unsigned short ldsA[2][64 * 64];   // 2 x 8 KB
    __shared__ unsigned short ldsB[2][64 * 64];   // 2 x 8 KB  (32 KB total)

    int totalgm = mb[En];
    int total = totalgm * NTN;

    int tid = threadIdx.x;
    int lane = tid & 63;
    int w = tid >> 6;
    int wm = (w >> 1) * 64, wn = (w & 1) * 64;
    int lr16 = lane & 15, lk = lane >> 4;
    int lj = lk * 4;

    // staging chunks: c = tid + i*256 (i=0,1) -> ldsrow = c>>3, ch = c&7;
    // involution ch' = ch ^ (ldsrow&7); global row = 2*ldsrow + (ch'>>2),
    // k-chunk = ch'&3. (i*256 preserves low 3 bits and ldsrow parity group.)
    int lrow0 = tid >> 3;            // 0..31
    int lrow1 = (tid + 256) >> 3;    // 32..63
    int ch0 = (tid & 7) ^ (lrow0 & 7);
    int ch1 = (tid & 7) ^ (lrow1 & 7);
    int grow0 = lrow0 * 2 + (ch0 >> 2), kc0 = ch0 & 3;
    int grow1 = lrow1 * 2 + (ch1 >> 2), kc1 = ch1 & 3;

    // fragment LDS offsets (elems, slot-relative), same involution
    int aoff[4], boff[4];
#pragma unroll
    for (int m = 0; m < 4; m++) {
        int row = wm + m * 16 + lr16;
        int lr = row >> 1;
        aoff[m] = lr * 64 + (((((row & 1) << 2) | lk) ^ (lr & 7)) << 3);
    }
#pragma unroll
    for (int n = 0; n < 4; n++) {
        int row = wn + n * 16 + lr16;
        int lr = row >> 1;
        boff[n] = lr * 64 + (((((row & 1) << 2) | lk) ^ (lr & 7)) << 3);
    }

    for (int v = blockIdx.x; v < total; v += gridDim.x) {
        int tile = swz_tile(v, total);
        int nt = tile / totalgm;           // nt-major: B panel shared in chunk
        int gm = tile - nt * totalgm;
        int e = find_e(mb, gm);
        int mtile = gm - mb[e];
        int M_e = cnt[e];
        int m0 = mtile * 128, n0 = nt * 128;
        int rowbase0 = base[e] + m0;
        const unsigned short* Ab = Ag + (size_t)rowbase0 * KDIM;
        const unsigned short* Bb = Bg + ((size_t)e * NOUT + n0) * KDIM;

        const unsigned short* aS0 = Ab + (size_t)grow0 * KDIM + kc0 * 8;
        const unsigned short* aS1 = Ab + (size_t)grow1 * KDIM + kc1 * 8;
        const unsigned short* bS0 = Bb + (size_t)grow0 * KDIM + kc0 * 8;
        const unsigned short* bS1 = Bb + (size_t)grow1 * KDIM + kc1 * 8;

        f32x4 acc[4][4];
#pragma unroll
        for (int m = 0; m < 4; m++)
#pragma unroll
            for (int n = 0; n < 4; n++) acc[m][n] = (f32x4){0.f, 0.f, 0.f, 0.f};

        auto stage = [&](int t) {
            char* sa = (char*)ldsA[t & 1];
            char* sb = (char*)ldsB[t & 1];
            int k0 = t * 32;
            gload_lds16(aS0 + k0, sa + tid * 16);
            gload_lds16(aS1 + k0, sa + (tid + 256) * 16);
            gload_lds16(bS0 + k0, sb + tid * 16);
            gload_lds16(bS1 + k0, sb + (tid + 256) * 16);
        };

        stage(0);

        for (int t = 0; t < NT; ++t) {
            waitvm0();               // sub-tile t's loads landed
            barrier_raw();           // all waves done reading slot t&1's prev use
            if (t + 1 < NT) stage(t + 1);
            asm volatile("" ::: "memory");
            const unsigned short* sa = ldsA[t & 1];
            const unsigned short* sb = ldsB[t & 1];
            bf16x8 a[4], b[4];
#pragma unroll
            for (int n = 0; n < 4; n++) b[n] = *(const bf16x8*)(sb + boff[n]);
#pragma unroll
            for (int m = 0; m < 4; m++) a[m] = *(const bf16x8*)(sa + aoff[m]);
            __builtin_amdgcn_s_setprio(1);
#pragma unroll
            for (int m = 0; m < 4; m++)
#pragma unroll
                for (int n = 0; n < 4; n++)
                    acc[m][n] = __builtin_amdgcn_mfma_f32_16x16x32_bf16(b[n], a[m], acc[m][n], 0, 0, 0);
            __builtin_amdgcn_s_setprio(0);
        }

        // ---- epilogue: lane holds row (lr16) x 4 consecutive cols ----
        const float* be = bias + (size_t)e * NOUT;
#pragma unroll
        for (int m = 0; m < 4; m++) {
            int rt = wm + m * 16 + lr16;
            if (m0 + rt < M_e) {
                size_t rowoff = (size_t)(rowbase0 + rt) * NOUT;
#pragma unroll
                for (int n = 0; n < 4; n++) {
                    int col0e = n0 + wn + n * 16 + lj;
                    float4 bs = *reinterpret_cast<const float4*>(be + col0e);
                    float v0 = acc[m][n][0] + bs.x;
                    float v1 = acc[m][n][1] + bs.y;
                    float v2 = acc[m][n][2] + bs.z;
                    float v3 = acc[m][n][3] + bs.w;
                    ushort4 u;
                    if constexpr (G1) {
                        u.x = f2bf(fmaxf(v0, 0.f));
                        u.y = f2bf(fmaxf(v1, 0.f));
                        u.z = f2bf(fmaxf(v2, 0.f));
                        u.w = f2bf(fmaxf(v3, 0.f));
                    } else {
                        u.x = f2bf(v0); u.y = f2bf(v1);
                        u.z = f2bf(v2); u.w = f2bf(v3);
                    }
                    *reinterpret_cast<ushort4*>(outb + rowoff + col0e) = u;
                }
            }
        }
    }
}

// ---------------- combine: out[t] = w0*y[r0] + w1*y[r1] (y bf16) ------------
__global__ __launch_bounds__(256) void combine_kernel(
    const unsigned short* __restrict__ y,
    const int* __restrict__ tok_e, const int* __restrict__ tok_pos,
    const int* __restrict__ base, const float* __restrict__ tok_w,
    float* __restrict__ out)
{
    int t = blockIdx.x, tid = threadIdx.x;
    int e0 = tok_e[2 * t], e1 = tok_e[2 * t + 1];
    int r0 = base[e0] + tok_pos[2 * t];
    int r1 = base[e1] + tok_pos[2 * t + 1];
    float w0 = tok_w[2 * t], w1 = tok_w[2 * t + 1];
    ushort4 a = *reinterpret_cast<const ushort4*>(y + (size_t)r0 * Dn + tid * 4);
    ushort4 b = *reinterpret_cast<const ushort4*>(y + (size_t)r1 * Dn + tid * 4);
    float4 o;
    o.x = w0 * bf2f(a.x) + w1 * bf2f(b.x);
    o.y = w0 * bf2f(a.y) + w1 * bf2f(b.y);
    o.z = w0 * bf2f(a.z) + w1 * bf2f(b.z);
    o.w = w0 * bf2f(a.w) + w1 * bf2f(b.w);
    *reinterpret_cast<float4*>(out + (size_t)t * Dn + tid * 4) = o;
}

// ---------------- launch ----------------------------------------------------
extern "C" void kernel_launch(void* const* d_in, const int* in_sizes, int n_in,
                              void* d_out, int out_size, void* d_ws, size_t ws_size,
                              hipStream_t stream)
{
    const float* x  = (const float*)d_in[0];
    const float* Wg = (const float*)d_in[1];
    const float* bg = (const float*)d_in[2];
    const float* W1 = (const float*)d_in[3];
    const float* b1 = (const float*)d_in[4];
    const float* W2 = (const float*)d_in[5];
    const float* b2 = (const float*)d_in[6];
    float* out = (float*)d_out;

    char* ws = (char*)d_ws;
    size_t off = 0;
    auto alloc = [&](size_t bytes) {
        size_t o = off; off += (bytes + 255) & ~(size_t)255; return o;
    };
    const int ROWS = Tn * 2;            // 16384 dispatch rows
    const int RCAP = ROWS + 256;        // slack for tile overreads

    unsigned short* Wt = (unsigned short*)(ws + alloc((size_t)En * Hn * Dn * 2)); // W1t then W2t
    unsigned short* xg = (unsigned short*)(ws + alloc((size_t)RCAP * Dn * 2));
    unsigned short* hg = (unsigned short*)(ws + alloc((size_t)RCAP * Hn * 2));
    unsigned short* yv = (unsigned short*)(ws + alloc((size_t)RCAP * Dn * 2));   // bf16 y
    int*   cnt     = (int*)(ws + alloc(En * 4));
    int*   base    = (int*)(ws + alloc((En + 1) * 4));
    int*   mb      = (int*)(ws + alloc((En + 1) * 4));
    int*   tok_e   = (int*)(ws + alloc(Tn * 2 * 4));
    int*   tok_pos = (int*)(ws + alloc(Tn * 2 * 4));
    float* tok_w   = (float*)(ws + alloc(Tn * 2 * 4));
    (void)ws_size; (void)in_sizes; (void)n_in; (void)out_size;

    hipMemsetAsync(cnt, 0, En * 4, stream);

    gate_kernel<<<Tn / 16, 256, 0, stream>>>(x, Wg, bg, cnt, tok_e, tok_pos, tok_w);
    scan_kernel<<<1, 64, 0, stream>>>(cnt, base, mb);
    gather_kernel<<<Tn, 256, 0, stream>>>(x, tok_e, tok_pos, base, xg);

    // W1 [E][Dn][Hn] -> Wt [E][Hn][Dn] bf16
    convT_kernel<<<dim3(Hn / 64, Dn / 64, En), 512, 0, stream>>>(W1, Wt, Dn, Hn);
    // gemm1: 128x128, 5 blocks/CU -> grid 1280, grid-stride
    gemm128_kernel<true><<<1280, 256, 0, stream>>>(
        xg, Wt, b1, hg, cnt, base, mb);

    // W2 [E][Hn][Dn] -> Wt [E][Dn][Hn] bf16
    convT_kernel<<<dim3(Dn / 64, Hn / 64, En), 512, 0, stream>>>(W2, Wt, Hn, Dn);
    // gemm2: K=4096 undivided, bf16 y out (units <= ~1144, single pass)
    gemm128_kernel<false><<<1280, 256, 0, stream>>>(
        hg, Wt, b2, yv, cnt, base, mb);

    combine_kernel<<<Tn, 256, 0, stream>>>(yv, tok_e, tok_pos, base, tok_w, out);
}

// Round 12
// 771.315 us; speedup vs baseline: 2.1638x; 2.1638x over previous
//
#include <hip/hip_runtime.h>
#include <hip/hip_bf16.h>
#include <stdint.h>

// MoE: T=8192, D=1024, H=4096, E=16, top-2. Sparse dispatch + bf16 MFMA GEMMs.
// GEMM core: 128x128 tiles, 256 thr (4 waves), BK=32 ring-2 LDS (32 KB),
// __launch_bounds__(256,4) -> 4 blocks/CU = 4 independent staging streams
// (R9 mechanism; R11's (256,5) forced a VGPR spill - fixed). Counted vmcnt(4)
// 2-barrier subtile loop. Packed 128B-row LDS + XOR involution (0 conflicts).

#define Tn 8192
#define Dn 1024
#define Hn 4096
#define En 16

typedef __attribute__((ext_vector_type(8))) short bf16x8;
typedef __attribute__((ext_vector_type(4))) float f32x4;

__device__ __forceinline__ unsigned short f2bf(float f) {
    union { __hip_bfloat16 h; unsigned short u; } cv;
    cv.h = __float2bfloat16(f);
    return cv.u;
}
__device__ __forceinline__ float bf2f(unsigned short u) {
    union { unsigned int i; float f; } cv;
    cv.i = ((unsigned int)u) << 16;
    return cv.f;
}

__device__ __forceinline__ void gload_lds16(const void* gptr, void* lptr) {
    __builtin_amdgcn_global_load_lds(
        (const __attribute__((address_space(1))) uint32_t*)gptr,
        (__attribute__((address_space(3))) uint32_t*)lptr, 16, 0, 0);
}

// bijective XCD-chunked swizzle (m204)
__device__ __forceinline__ int swz_tile(int v, int total) {
    int q = total >> 3, r = total & 7;
    int x = v & 7, k = v >> 3;
    int b = (x < r) ? x * (q + 1) : r * (q + 1) + (x - r) * q;
    return b + k;
}

// e = #{i in [1,En) : mb[i] <= gm}
__device__ __forceinline__ int find_e(const int* __restrict__ mb, int gm) {
    int e = 0;
#pragma unroll
    for (int i = 1; i < En; i++) e += (mb[i] <= gm) ? 1 : 0;
    return e;
}

__device__ __forceinline__ void waitvm4()  { asm volatile("s_waitcnt vmcnt(4)" ::: "memory"); }
__device__ __forceinline__ void waitvm0()  { asm volatile("s_waitcnt vmcnt(0)" ::: "memory"); }
__device__ __forceinline__ void barrier_raw() { asm volatile("s_barrier" ::: "memory"); }

__device__ __forceinline__ bool better(float va, int ia, float vb, int ib) {
    return (va > vb) || (va == vb && ia < ib);
}

// ---------------- gate: 16 tokens/block, Wg in LDS, shuffle top-2 -----------
__global__ __launch_bounds__(256) void gate_kernel(
    const float* __restrict__ x, const float* __restrict__ Wg,
    const float* __restrict__ bg,
    int* cnt, int* tok_e, int* tok_pos, float* tok_w)
{
    __shared__ float wgt[16 * 1028];
    int tid = threadIdx.x;
    int t0 = blockIdx.x * 16;

#pragma unroll
    for (int i = 0; i < 64; i++) {
        int idx = i * 256 + tid;
        int k = idx >> 4, e = idx & 15;
        wgt[e * 1028 + k] = Wg[idx];
    }
    __syncthreads();

    int tok = tid >> 4, e = tid & 15;
    const float4* xr = reinterpret_cast<const float4*>(x + (size_t)(t0 + tok) * Dn);
    const float4* wr = reinterpret_cast<const float4*>(&wgt[e * 1028]);
    float acc = 0.f;
#pragma unroll 8
    for (int q = 0; q < 256; q++) {
        float4 xv = xr[q], wv = wr[q];
        acc += xv.x * wv.x + xv.y * wv.y + xv.z * wv.z + xv.w * wv.w;
    }
    acc += bg[e];

    float v0 = acc, v1 = -1e30f;
    int i0 = e, i1 = -1;
#pragma unroll
    for (int m = 1; m < 16; m <<= 1) {
        float ov0 = __shfl_xor(v0, m, 16); int oi0 = __shfl_xor(i0, m, 16);
        float ov1 = __shfl_xor(v1, m, 16); int oi1 = __shfl_xor(i1, m, 16);
        if (better(ov0, oi0, v0, i0)) {
            if (better(v0, i0, ov1, oi1)) { v1 = v0; i1 = i0; }
            else                          { v1 = ov1; i1 = oi1; }
            v0 = ov0; i0 = oi0;
        } else if (better(ov0, oi0, v1, i1)) {
            v1 = ov0; i1 = oi0;
        }
    }
    if (e == 0) {
        float ex = __expf(v1 - v0);
        float w0 = 1.f / (1.f + ex);
        float w1 = ex / (1.f + ex);
        int p0 = atomicAdd(&cnt[i0], 1);
        int p1 = atomicAdd(&cnt[i1], 1);
        int t = t0 + tok;
        tok_e[t * 2 + 0] = i0; tok_e[t * 2 + 1] = i1;
        tok_pos[t * 2 + 0] = p0; tok_pos[t * 2 + 1] = p1;
        tok_w[t * 2 + 0] = w0; tok_w[t * 2 + 1] = w1;
    }
}

// ---------------- scan: row bases + cumulative 128-row mtiles ---------------
__global__ void scan_kernel(const int* cnt, int* base, int* mb)
{
    if (threadIdx.x == 0 && blockIdx.x == 0) {
        int b = 0, m = 0;
        for (int e = 0; e < En; e++) {
            base[e] = b; mb[e] = m;
            b += cnt[e];
            m += (cnt[e] + 127) >> 7;
        }
        base[En] = b; mb[En] = m;
    }
}

// ---------------- gather ----------------------------------------------------
__global__ __launch_bounds__(256) void gather_kernel(
    const float* __restrict__ x, const int* tok_e, const int* tok_pos,
    const int* base, unsigned short* xg)
{
    int t = blockIdx.x; int tid = threadIdx.x;
    int e0 = tok_e[2 * t], e1 = tok_e[2 * t + 1];
    int r0 = base[e0] + tok_pos[2 * t];
    int r1 = base[e1] + tok_pos[2 * t + 1];
    float4 v = *reinterpret_cast<const float4*>(x + (size_t)t * Dn + tid * 4);
    ushort4 u;
    u.x = f2bf(v.x); u.y = f2bf(v.y); u.z = f2bf(v.z); u.w = f2bf(v.w);
    *reinterpret_cast<ushort4*>(xg + (size_t)r0 * Dn + tid * 4) = u;
    *reinterpret_cast<ushort4*>(xg + (size_t)r1 * Dn + tid * 4) = u;
}

// ---------------- convT: [R][C] f32 -> [C][R] bf16, 64x64 tiles -------------
__global__ __launch_bounds__(512) void convT_kernel(
    const float* __restrict__ src, unsigned short* __restrict__ dst, int R, int C)
{
    int e = blockIdx.z;
    const float* s = src + (size_t)e * R * C;
    unsigned short* d = dst + (size_t)e * R * C;
    __shared__ float tile[64][65];
    int r0 = blockIdx.y * 64, c0 = blockIdx.x * 64;
    int tr = threadIdx.x >> 4;
    int tc4 = (threadIdx.x & 15) * 4;
    float4 v0 = *reinterpret_cast<const float4*>(s + (size_t)(r0 + tr) * C + c0 + tc4);
    float4 v1 = *reinterpret_cast<const float4*>(s + (size_t)(r0 + tr + 32) * C + c0 + tc4);
    tile[tr][tc4 + 0] = v0.x; tile[tr][tc4 + 1] = v0.y;
    tile[tr][tc4 + 2] = v0.z; tile[tr][tc4 + 3] = v0.w;
    tile[tr + 32][tc4 + 0] = v1.x; tile[tr + 32][tc4 + 1] = v1.y;
    tile[tr + 32][tc4 + 2] = v1.z; tile[tr + 32][tc4 + 3] = v1.w;
    __syncthreads();
    ushort4 u0, u1;
    u0.x = f2bf(tile[tc4 + 0][tr]);      u1.x = f2bf(tile[tc4 + 0][tr + 32]);
    u0.y = f2bf(tile[tc4 + 1][tr]);      u1.y = f2bf(tile[tc4 + 1][tr + 32]);
    u0.z = f2bf(tile[tc4 + 2][tr]);      u1.z = f2bf(tile[tc4 + 2][tr + 32]);
    u0.w = f2bf(tile[tc4 + 3][tr]);      u1.w = f2bf(tile[tc4 + 3][tr + 32]);
    *reinterpret_cast<ushort4*>(d + (size_t)(c0 + tr) * R + r0 + tc4) = u0;
    *reinterpret_cast<ushort4*>(d + (size_t)(c0 + tr + 32) * R + r0 + tc4) = u1;
}

// ---------------- 128x128 GEMM, 4 waves, BK=32 ring-2, 4 blocks/CU ----------
// Packed LDS: tile 128 rows x 32 k -> ldsrow = row>>1 (64 x 128B rows),
// chunk ch = ((row&1)<<2 | k/8) ^ (ldsrow&7)  [involution both sides -> 0
// conflicts, proven R11]. Counted vmcnt(4): one subtile always in flight.
// Two barriers per subtile (ring-2: stage(t+2) overwrites compute(t)'s slot).
// nt-major inside XCD chunk (B panel L2-shared). G1: relu->bf16. G2: bf16 y.
template<bool G1>
__global__ __launch_bounds__(256, 4) void gemm128_kernel(
    const unsigned short* __restrict__ Ag, const unsigned short* __restrict__ Bg,
    const float* __restrict__ bias, unsigned short* __restrict__ outb,
    const int* __restrict__ cnt, const int* __restrict__ base,
    const int* __restrict__ mb)
{
    constexpr int KDIM = G1 ? Dn : Hn;
    constexpr int NOUT = G1 ? Hn : Dn;
    constexpr int NTN = NOUT / 128;        // n-tiles
    constexpr int NT = KDIM / 32;          // K sub-tiles
    __shared__ unsigned short ldsA[2][64 * 64];   // 2 x 8 KB
    __shared__ unsigned short ldsB[2][64 * 64];   // 2 x 8 KB  (32 KB total)

    int totalgm = mb[En];
    int total = totalgm * NTN;

    int tid = threadIdx.x;
    int lane = tid & 63;
    int w = tid >> 6;
    int wm = (w >> 1) * 64, wn = (w & 1) * 64;
    int lr16 = lane & 15, lk = lane >> 4;
    int lj = lk * 4;

    // staging chunks: c = tid + i*256 (i=0,1) -> ldsrow = c>>3, ch = c&7;
    // involution ch' = ch ^ (ldsrow&7); global row = 2*ldsrow + (ch'>>2),
    // k-chunk = ch'&3.
    int lrow0 = tid >> 3;            // 0..31
    int lrow1 = (tid + 256) >> 3;    // 32..63
    int ch0 = (tid & 7) ^ (lrow0 & 7);
    int ch1 = (tid & 7) ^ (lrow1 & 7);
    int grow0 = lrow0 * 2 + (ch0 >> 2), kc0 = ch0 & 3;
    int grow1 = lrow1 * 2 + (ch1 >> 2), kc1 = ch1 & 3;

    // fragment LDS offsets (elems, slot-relative), same involution
    int aoff[4], boff[4];
#pragma unroll
    for (int m = 0; m < 4; m++) {
        int row = wm + m * 16 + lr16;
        int lr = row >> 1;
        aoff[m] = lr * 64 + (((((row & 1) << 2) | lk) ^ (lr & 7)) << 3);
    }
#pragma unroll
    for (int n = 0; n < 4; n++) {
        int row = wn + n * 16 + lr16;
        int lr = row >> 1;
        boff[n] = lr * 64 + (((((row & 1) << 2) | lk) ^ (lr & 7)) << 3);
    }

    for (int v = blockIdx.x; v < total; v += gridDim.x) {
        int tile = swz_tile(v, total);
        int nt = tile / totalgm;           // nt-major: B panel shared in chunk
        int gm = tile - nt * totalgm;
        int e = find_e(mb, gm);
        int mtile = gm - mb[e];
        int M_e = cnt[e];
        int m0 = mtile * 128, n0 = nt * 128;
        int rowbase0 = base[e] + m0;
        const unsigned short* Ab = Ag + (size_t)rowbase0 * KDIM;
        const unsigned short* Bb = Bg + ((size_t)e * NOUT + n0) * KDIM;

        const unsigned short* aS0 = Ab + (size_t)grow0 * KDIM + kc0 * 8;
        const unsigned short* aS1 = Ab + (size_t)grow1 * KDIM + kc1 * 8;
        const unsigned short* bS0 = Bb + (size_t)grow0 * KDIM + kc0 * 8;
        const unsigned short* bS1 = Bb + (size_t)grow1 * KDIM + kc1 * 8;

        f32x4 acc[4][4];
#pragma unroll
        for (int m = 0; m < 4; m++)
#pragma unroll
            for (int n = 0; n < 4; n++) acc[m][n] = (f32x4){0.f, 0.f, 0.f, 0.f};

        auto stage = [&](int t) {
            char* sa = (char*)ldsA[t & 1];
            char* sb = (char*)ldsB[t & 1];
            int k0 = t * 32;
            gload_lds16(aS0 + k0, sa + tid * 16);
            gload_lds16(aS1 + k0, sa + (tid + 256) * 16);
            gload_lds16(bS0 + k0, sb + tid * 16);
            gload_lds16(bS1 + k0, sb + (tid + 256) * 16);
        };

        stage(0);
        stage(1);

        for (int t = 0; t < NT; ++t) {
            if (t + 1 < NT) waitvm4();   // subtile t landed; t+1 stays in flight
            else            waitvm0();
            barrier_raw();
            const unsigned short* sa = ldsA[t & 1];
            const unsigned short* sb = ldsB[t & 1];
            bf16x8 a[4], b[4];
#pragma unroll
            for (int n = 0; n < 4; n++) b[n] = *(const bf16x8*)(sb + boff[n]);
#pragma unroll
            for (int m = 0; m < 4; m++) a[m] = *(const bf16x8*)(sa + aoff[m]);
            __builtin_amdgcn_s_setprio(1);
#pragma unroll
            for (int m = 0; m < 4; m++)
#pragma unroll
                for (int n = 0; n < 4; n++)
                    acc[m][n] = __builtin_amdgcn_mfma_f32_16x16x32_bf16(b[n], a[m], acc[m][n], 0, 0, 0);
            __builtin_amdgcn_s_setprio(0);
            barrier_raw();               // all waves finished reading slot t&1
            if (t + 2 < NT) stage(t + 2);
        }

        // ---- epilogue: lane holds row (lr16) x 4 consecutive cols ----
        const float* be = bias + (size_t)e * NOUT;
#pragma unroll
        for (int m = 0; m < 4; m++) {
            int rt = wm + m * 16 + lr16;
            if (m0 + rt < M_e) {
                size_t rowoff = (size_t)(rowbase0 + rt) * NOUT;
#pragma unroll
                for (int n = 0; n < 4; n++) {
                    int col0e = n0 + wn + n * 16 + lj;
                    float4 bs = *reinterpret_cast<const float4*>(be + col0e);
                    float v0 = acc[m][n][0] + bs.x;
                    float v1 = acc[m][n][1] + bs.y;
                    float v2 = acc[m][n][2] + bs.z;
                    float v3 = acc[m][n][3] + bs.w;
                    ushort4 u;
                    if constexpr (G1) {
                        u.x = f2bf(fmaxf(v0, 0.f));
                        u.y = f2bf(fmaxf(v1, 0.f));
                        u.z = f2bf(fmaxf(v2, 0.f));
                        u.w = f2bf(fmaxf(v3, 0.f));
                    } else {
                        u.x = f2bf(v0); u.y = f2bf(v1);
                        u.z = f2bf(v2); u.w = f2bf(v3);
                    }
                    *reinterpret_cast<ushort4*>(outb + rowoff + col0e) = u;
                }
            }
        }
    }
}

// ---------------- combine: out[t] = w0*y[r0] + w1*y[r1] (y bf16) ------------
__global__ __launch_bounds__(256) void combine_kernel(
    const unsigned short* __restrict__ y,
    const int* __restrict__ tok_e, const int* __restrict__ tok_pos,
    const int* __restrict__ base, const float* __restrict__ tok_w,
    float* __restrict__ out)
{
    int t = blockIdx.x, tid = threadIdx.x;
    int e0 = tok_e[2 * t], e1 = tok_e[2 * t + 1];
    int r0 = base[e0] + tok_pos[2 * t];
    int r1 = base[e1] + tok_pos[2 * t + 1];
    float w0 = tok_w[2 * t], w1 = tok_w[2 * t + 1];
    ushort4 a = *reinterpret_cast<const ushort4*>(y + (size_t)r0 * Dn + tid * 4);
    ushort4 b = *reinterpret_cast<const ushort4*>(y + (size_t)r1 * Dn + tid * 4);
    float4 o;
    o.x = w0 * bf2f(a.x) + w1 * bf2f(b.x);
    o.y = w0 * bf2f(a.y) + w1 * bf2f(b.y);
    o.z = w0 * bf2f(a.z) + w1 * bf2f(b.z);
    o.w = w0 * bf2f(a.w) + w1 * bf2f(b.w);
    *reinterpret_cast<float4*>(out + (size_t)t * Dn + tid * 4) = o;
}

// ---------------- launch ----------------------------------------------------
extern "C" void kernel_launch(void* const* d_in, const int* in_sizes, int n_in,
                              void* d_out, int out_size, void* d_ws, size_t ws_size,
                              hipStream_t stream)
{
    const float* x  = (const float*)d_in[0];
    const float* Wg = (const float*)d_in[1];
    const float* bg = (const float*)d_in[2];
    const float* W1 = (const float*)d_in[3];
    const float* b1 = (const float*)d_in[4];
    const float* W2 = (const float*)d_in[5];
    const float* b2 = (const float*)d_in[6];
    float* out = (float*)d_out;

    char* ws = (char*)d_ws;
    size_t off = 0;
    auto alloc = [&](size_t bytes) {
        size_t o = off; off += (bytes + 255) & ~(size_t)255; return o;
    };
    const int ROWS = Tn * 2;            // 16384 dispatch rows
    const int RCAP = ROWS + 256;        // slack for tile overreads

    unsigned short* Wt = (unsigned short*)(ws + alloc((size_t)En * Hn * Dn * 2)); // W1t then W2t
    unsigned short* xg = (unsigned short*)(ws + alloc((size_t)RCAP * Dn * 2));
    unsigned short* hg = (unsigned short*)(ws + alloc((size_t)RCAP * Hn * 2));
    unsigned short* yv = (unsigned short*)(ws + alloc((size_t)RCAP * Dn * 2));   // bf16 y
    int*   cnt     = (int*)(ws + alloc(En * 4));
    int*   base    = (int*)(ws + alloc((En + 1) * 4));
    int*   mb      = (int*)(ws + alloc((En + 1) * 4));
    int*   tok_e   = (int*)(ws + alloc(Tn * 2 * 4));
    int*   tok_pos = (int*)(ws + alloc(Tn * 2 * 4));
    float* tok_w   = (float*)(ws + alloc(Tn * 2 * 4));
    (void)ws_size; (void)in_sizes; (void)n_in; (void)out_size;

    hipMemsetAsync(cnt, 0, En * 4, stream);

    gate_kernel<<<Tn / 16, 256, 0, stream>>>(x, Wg, bg, cnt, tok_e, tok_pos, tok_w);
    scan_kernel<<<1, 64, 0, stream>>>(cnt, base, mb);
    gather_kernel<<<Tn, 256, 0, stream>>>(x, tok_e, tok_pos, base, xg);

    // W1 [E][Dn][Hn] -> Wt [E][Hn][Dn] bf16
    convT_kernel<<<dim3(Hn / 64, Dn / 64, En), 512, 0, stream>>>(W1, Wt, Dn, Hn);
    // gemm1: 128x128, 4 blocks/CU -> grid 1024, grid-stride
    gemm128_kernel<true><<<1024, 256, 0, stream>>>(
        xg, Wt, b1, hg, cnt, base, mb);

    // W2 [E][Hn][Dn] -> Wt [E][Dn][Hn] bf16
    convT_kernel<<<dim3(Dn / 64, Hn / 64, En), 512, 0, stream>>>(W2, Wt, Hn, Dn);
    // gemm2: K=4096 undivided, bf16 y out
    gemm128_kernel<false><<<1024, 256, 0, stream>>>(
        hg, Wt, b2, yv, cnt, base, mb);

    combine_kernel<<<Tn, 256, 0, stream>>>(yv, tok_e, tok_pos, base, tok_w, out);
}

// Round 13
// 712.131 us; speedup vs baseline: 2.3436x; 1.0831x over previous
//
#include <hip/hip_runtime.h>
#include <hip/hip_bf16.h>
#include <stdint.h>

// MoE: T=8192, D=1024, H=4096, E=16, top-2. Sparse dispatch + bf16 MFMA GEMMs.
// GEMM core: 128x128 tiles, 4 waves, BK=32 ring-2 (32 KB), 4 blocks/CU,
// packed 128B-row LDS + XOR involution (0 conflicts), counted vmcnt(4).
// THIS ROUND (single change vs R12): gm-major/nt-fastest tile order ->
// A panel (256 KB) L2-resident across its nt sweep; re-read object = weights
// (128 MB, alone L3-resident; no 264MB thrash). Cuts FETCH amplification.

#define Tn 8192
#define Dn 1024
#define Hn 4096
#define En 16

typedef __attribute__((ext_vector_type(8))) short bf16x8;
typedef __attribute__((ext_vector_type(4))) float f32x4;

__device__ __forceinline__ unsigned short f2bf(float f) {
    union { __hip_bfloat16 h; unsigned short u; } cv;
    cv.h = __float2bfloat16(f);
    return cv.u;
}
__device__ __forceinline__ float bf2f(unsigned short u) {
    union { unsigned int i; float f; } cv;
    cv.i = ((unsigned int)u) << 16;
    return cv.f;
}

__device__ __forceinline__ void gload_lds16(const void* gptr, void* lptr) {
    __builtin_amdgcn_global_load_lds(
        (const __attribute__((address_space(1))) uint32_t*)gptr,
        (__attribute__((address_space(3))) uint32_t*)lptr, 16, 0, 0);
}

// bijective XCD-chunked swizzle (m204)
__device__ __forceinline__ int swz_tile(int v, int total) {
    int q = total >> 3, r = total & 7;
    int x = v & 7, k = v >> 3;
    int b = (x < r) ? x * (q + 1) : r * (q + 1) + (x - r) * q;
    return b + k;
}

// e = #{i in [1,En) : mb[i] <= gm}
__device__ __forceinline__ int find_e(const int* __restrict__ mb, int gm) {
    int e = 0;
#pragma unroll
    for (int i = 1; i < En; i++) e += (mb[i] <= gm) ? 1 : 0;
    return e;
}

__device__ __forceinline__ void waitvm4()  { asm volatile("s_waitcnt vmcnt(4)" ::: "memory"); }
__device__ __forceinline__ void waitvm0()  { asm volatile("s_waitcnt vmcnt(0)" ::: "memory"); }
__device__ __forceinline__ void barrier_raw() { asm volatile("s_barrier" ::: "memory"); }

__device__ __forceinline__ bool better(float va, int ia, float vb, int ib) {
    return (va > vb) || (va == vb && ia < ib);
}

// ---------------- gate: 16 tokens/block, Wg in LDS, shuffle top-2 -----------
__global__ __launch_bounds__(256) void gate_kernel(
    const float* __restrict__ x, const float* __restrict__ Wg,
    const float* __restrict__ bg,
    int* cnt, int* tok_e, int* tok_pos, float* tok_w)
{
    __shared__ float wgt[16 * 1028];
    int tid = threadIdx.x;
    int t0 = blockIdx.x * 16;

#pragma unroll
    for (int i = 0; i < 64; i++) {
        int idx = i * 256 + tid;
        int k = idx >> 4, e = idx & 15;
        wgt[e * 1028 + k] = Wg[idx];
    }
    __syncthreads();

    int tok = tid >> 4, e = tid & 15;
    const float4* xr = reinterpret_cast<const float4*>(x + (size_t)(t0 + tok) * Dn);
    const float4* wr = reinterpret_cast<const float4*>(&wgt[e * 1028]);
    float acc = 0.f;
#pragma unroll 8
    for (int q = 0; q < 256; q++) {
        float4 xv = xr[q], wv = wr[q];
        acc += xv.x * wv.x + xv.y * wv.y + xv.z * wv.z + xv.w * wv.w;
    }
    acc += bg[e];

    float v0 = acc, v1 = -1e30f;
    int i0 = e, i1 = -1;
#pragma unroll
    for (int m = 1; m < 16; m <<= 1) {
        float ov0 = __shfl_xor(v0, m, 16); int oi0 = __shfl_xor(i0, m, 16);
        float ov1 = __shfl_xor(v1, m, 16); int oi1 = __shfl_xor(i1, m, 16);
        if (better(ov0, oi0, v0, i0)) {
            if (better(v0, i0, ov1, oi1)) { v1 = v0; i1 = i0; }
            else                          { v1 = ov1; i1 = oi1; }
            v0 = ov0; i0 = oi0;
        } else if (better(ov0, oi0, v1, i1)) {
            v1 = ov0; i1 = oi0;
        }
    }
    if (e == 0) {
        float ex = __expf(v1 - v0);
        float w0 = 1.f / (1.f + ex);
        float w1 = ex / (1.f + ex);
        int p0 = atomicAdd(&cnt[i0], 1);
        int p1 = atomicAdd(&cnt[i1], 1);
        int t = t0 + tok;
        tok_e[t * 2 + 0] = i0; tok_e[t * 2 + 1] = i1;
        tok_pos[t * 2 + 0] = p0; tok_pos[t * 2 + 1] = p1;
        tok_w[t * 2 + 0] = w0; tok_w[t * 2 + 1] = w1;
    }
}

// ---------------- scan: row bases + cumulative 128-row mtiles ---------------
__global__ void scan_kernel(const int* cnt, int* base, int* mb)
{
    if (threadIdx.x == 0 && blockIdx.x == 0) {
        int b = 0, m = 0;
        for (int e = 0; e < En; e++) {
            base[e] = b; mb[e] = m;
            b += cnt[e];
            m += (cnt[e] + 127) >> 7;
        }
        base[En] = b; mb[En] = m;
    }
}

// ---------------- gather ----------------------------------------------------
__global__ __launch_bounds__(256) void gather_kernel(
    const float* __restrict__ x, const int* tok_e, const int* tok_pos,
    const int* base, unsigned short* xg)
{
    int t = blockIdx.x; int tid = threadIdx.x;
    int e0 = tok_e[2 * t], e1 = tok_e[2 * t + 1];
    int r0 = base[e0] + tok_pos[2 * t];
    int r1 = base[e1] + tok_pos[2 * t + 1];
    float4 v = *reinterpret_cast<const float4*>(x + (size_t)t * Dn + tid * 4);
    ushort4 u;
    u.x = f2bf(v.x); u.y = f2bf(v.y); u.z = f2bf(v.z); u.w = f2bf(v.w);
    *reinterpret_cast<ushort4*>(xg + (size_t)r0 * Dn + tid * 4) = u;
    *reinterpret_cast<ushort4*>(xg + (size_t)r1 * Dn + tid * 4) = u;
}

// ---------------- convT: [R][C] f32 -> [C][R] bf16, 64x64 tiles -------------
__global__ __launch_bounds__(512) void convT_kernel(
    const float* __restrict__ src, unsigned short* __restrict__ dst, int R, int C)
{
    int e = blockIdx.z;
    const float* s = src + (size_t)e * R * C;
    unsigned short* d = dst + (size_t)e * R * C;
    __shared__ float tile[64][65];
    int r0 = blockIdx.y * 64, c0 = blockIdx.x * 64;
    int tr = threadIdx.x >> 4;
    int tc4 = (threadIdx.x & 15) * 4;
    float4 v0 = *reinterpret_cast<const float4*>(s + (size_t)(r0 + tr) * C + c0 + tc4);
    float4 v1 = *reinterpret_cast<const float4*>(s + (size_t)(r0 + tr + 32) * C + c0 + tc4);
    tile[tr][tc4 + 0] = v0.x; tile[tr][tc4 + 1] = v0.y;
    tile[tr][tc4 + 2] = v0.z; tile[tr][tc4 + 3] = v0.w;
    tile[tr + 32][tc4 + 0] = v1.x; tile[tr + 32][tc4 + 1] = v1.y;
    tile[tr + 32][tc4 + 2] = v1.z; tile[tr + 32][tc4 + 3] = v1.w;
    __syncthreads();
    ushort4 u0, u1;
    u0.x = f2bf(tile[tc4 + 0][tr]);      u1.x = f2bf(tile[tc4 + 0][tr + 32]);
    u0.y = f2bf(tile[tc4 + 1][tr]);      u1.y = f2bf(tile[tc4 + 1][tr + 32]);
    u0.z = f2bf(tile[tc4 + 2][tr]);      u1.z = f2bf(tile[tc4 + 2][tr + 32]);
    u0.w = f2bf(tile[tc4 + 3][tr]);      u1.w = f2bf(tile[tc4 + 3][tr + 32]);
    *reinterpret_cast<ushort4*>(d + (size_t)(c0 + tr) * R + r0 + tc4) = u0;
    *reinterpret_cast<ushort4*>(d + (size_t)(c0 + tr + 32) * R + r0 + tc4) = u1;
}

// ---------------- 128x128 GEMM, 4 waves, BK=32 ring-2, 4 blocks/CU ----------
// gm-major decode: tile = gm*NTN + nt (nt fastest). Within an XCD chunk the
// A panel (256 KB) stays L2-resident across its nt sweep; weights (128 MB)
// are the only L3-resident re-read object. Packed LDS + XOR involution.
template<bool G1>
__global__ __launch_bounds__(256, 4) void gemm128_kernel(
    const unsigned short* __restrict__ Ag, const unsigned short* __restrict__ Bg,
    const float* __restrict__ bias, unsigned short* __restrict__ outb,
    const int* __restrict__ cnt, const int* __restrict__ base,
    const int* __restrict__ mb)
{
    constexpr int KDIM = G1 ? Dn : Hn;
    constexpr int NOUT = G1 ? Hn : Dn;
    constexpr int NTN = NOUT / 128;        // n-tiles
    constexpr int NT = KDIM / 32;          // K sub-tiles
    __shared__ unsigned short ldsA[2][64 * 64];   // 2 x 8 KB
    __shared__ unsigned short ldsB[2][64 * 64];   // 2 x 8 KB  (32 KB total)

    int totalgm = mb[En];
    int total = totalgm * NTN;

    int tid = threadIdx.x;
    int lane = tid & 63;
    int w = tid >> 6;
    int wm = (w >> 1) * 64, wn = (w & 1) * 64;
    int lr16 = lane & 15, lk = lane >> 4;
    int lj = lk * 4;

    // staging chunks: c = tid + i*256 (i=0,1) -> ldsrow = c>>3, ch = c&7;
    // involution ch' = ch ^ (ldsrow&7); global row = 2*ldsrow + (ch'>>2),
    // k-chunk = ch'&3.
    int lrow0 = tid >> 3;            // 0..31
    int lrow1 = (tid + 256) >> 3;    // 32..63
    int ch0 = (tid & 7) ^ (lrow0 & 7);
    int ch1 = (tid & 7) ^ (lrow1 & 7);
    int grow0 = lrow0 * 2 + (ch0 >> 2), kc0 = ch0 & 3;
    int grow1 = lrow1 * 2 + (ch1 >> 2), kc1 = ch1 & 3;

    // fragment LDS offsets (elems, slot-relative), same involution
    int aoff[4], boff[4];
#pragma unroll
    for (int m = 0; m < 4; m++) {
        int row = wm + m * 16 + lr16;
        int lr = row >> 1;
        aoff[m] = lr * 64 + (((((row & 1) << 2) | lk) ^ (lr & 7)) << 3);
    }
#pragma unroll
    for (int n = 0; n < 4; n++) {
        int row = wn + n * 16 + lr16;
        int lr = row >> 1;
        boff[n] = lr * 64 + (((((row & 1) << 2) | lk) ^ (lr & 7)) << 3);
    }

    for (int v = blockIdx.x; v < total; v += gridDim.x) {
        int tile = swz_tile(v, total);
        int gm = tile / NTN;               // gm-major: A panel L2-shared
        int nt = tile % NTN;               // nt fastest within chunk
        int e = find_e(mb, gm);
        int mtile = gm - mb[e];
        int M_e = cnt[e];
        int m0 = mtile * 128, n0 = nt * 128;
        int rowbase0 = base[e] + m0;
        const unsigned short* Ab = Ag + (size_t)rowbase0 * KDIM;
        const unsigned short* Bb = Bg + ((size_t)e * NOUT + n0) * KDIM;

        const unsigned short* aS0 = Ab + (size_t)grow0 * KDIM + kc0 * 8;
        const unsigned short* aS1 = Ab + (size_t)grow1 * KDIM + kc1 * 8;
        const unsigned short* bS0 = Bb + (size_t)grow0 * KDIM + kc0 * 8;
        const unsigned short* bS1 = Bb + (size_t)grow1 * KDIM + kc1 * 8;

        f32x4 acc[4][4];
#pragma unroll
        for (int m = 0; m < 4; m++)
#pragma unroll
            for (int n = 0; n < 4; n++) acc[m][n] = (f32x4){0.f, 0.f, 0.f, 0.f};

        auto stage = [&](int t) {
            char* sa = (char*)ldsA[t & 1];
            char* sb = (char*)ldsB[t & 1];
            int k0 = t * 32;
            gload_lds16(aS0 + k0, sa + tid * 16);
            gload_lds16(aS1 + k0, sa + (tid + 256) * 16);
            gload_lds16(bS0 + k0, sb + tid * 16);
            gload_lds16(bS1 + k0, sb + (tid + 256) * 16);
        };

        stage(0);
        stage(1);

        for (int t = 0; t < NT; ++t) {
            if (t + 1 < NT) waitvm4();   // subtile t landed; t+1 stays in flight
            else            waitvm0();
            barrier_raw();
            const unsigned short* sa = ldsA[t & 1];
            const unsigned short* sb = ldsB[t & 1];
            bf16x8 a[4], b[4];
#pragma unroll
            for (int n = 0; n < 4; n++) b[n] = *(const bf16x8*)(sb + boff[n]);
#pragma unroll
            for (int m = 0; m < 4; m++) a[m] = *(const bf16x8*)(sa + aoff[m]);
            __builtin_amdgcn_s_setprio(1);
#pragma unroll
            for (int m = 0; m < 4; m++)
#pragma unroll
                for (int n = 0; n < 4; n++)
                    acc[m][n] = __builtin_amdgcn_mfma_f32_16x16x32_bf16(b[n], a[m], acc[m][n], 0, 0, 0);
            __builtin_amdgcn_s_setprio(0);
            barrier_raw();               // all waves finished reading slot t&1
            if (t + 2 < NT) stage(t + 2);
        }

        // ---- epilogue: lane holds row (lr16) x 4 consecutive cols ----
        const float* be = bias + (size_t)e * NOUT;
#pragma unroll
        for (int m = 0; m < 4; m++) {
            int rt = wm + m * 16 + lr16;
            if (m0 + rt < M_e) {
                size_t rowoff = (size_t)(rowbase0 + rt) * NOUT;
#pragma unroll
                for (int n = 0; n < 4; n++) {
                    int col0e = n0 + wn + n * 16 + lj;
                    float4 bs = *reinterpret_cast<const float4*>(be + col0e);
                    float v0 = acc[m][n][0] + bs.x;
                    float v1 = acc[m][n][1] + bs.y;
                    float v2 = acc[m][n][2] + bs.z;
                    float v3 = acc[m][n][3] + bs.w;
                    ushort4 u;
                    if constexpr (G1) {
                        u.x = f2bf(fmaxf(v0, 0.f));
                        u.y = f2bf(fmaxf(v1, 0.f));
                        u.z = f2bf(fmaxf(v2, 0.f));
                        u.w = f2bf(fmaxf(v3, 0.f));
                    } else {
                        u.x = f2bf(v0); u.y = f2bf(v1);
                        u.z = f2bf(v2); u.w = f2bf(v3);
                    }
                    *reinterpret_cast<ushort4*>(outb + rowoff + col0e) = u;
                }
            }
        }
    }
}

// ---------------- combine: out[t] = w0*y[r0] + w1*y[r1] (y bf16) ------------
__global__ __launch_bounds__(256) void combine_kernel(
    const unsigned short* __restrict__ y,
    const int* __restrict__ tok_e, const int* __restrict__ tok_pos,
    const int* __restrict__ base, const float* __restrict__ tok_w,
    float* __restrict__ out)
{
    int t = blockIdx.x, tid = threadIdx.x;
    int e0 = tok_e[2 * t], e1 = tok_e[2 * t + 1];
    int r0 = base[e0] + tok_pos[2 * t];
    int r1 = base[e1] + tok_pos[2 * t + 1];
    float w0 = tok_w[2 * t], w1 = tok_w[2 * t + 1];
    ushort4 a = *reinterpret_cast<const ushort4*>(y + (size_t)r0 * Dn + tid * 4);
    ushort4 b = *reinterpret_cast<const ushort4*>(y + (size_t)r1 * Dn + tid * 4);
    float4 o;
    o.x = w0 * bf2f(a.x) + w1 * bf2f(b.x);
    o.y = w0 * bf2f(a.y) + w1 * bf2f(b.y);
    o.z = w0 * bf2f(a.z) + w1 * bf2f(b.z);
    o.w = w0 * bf2f(a.w) + w1 * bf2f(b.w);
    *reinterpret_cast<float4*>(out + (size_t)t * Dn + tid * 4) = o;
}

// ---------------- launch ----------------------------------------------------
extern "C" void kernel_launch(void* const* d_in, const int* in_sizes, int n_in,
                              void* d_out, int out_size, void* d_ws, size_t ws_size,
                              hipStream_t stream)
{
    const float* x  = (const float*)d_in[0];
    const float* Wg = (const float*)d_in[1];
    const float* bg = (const float*)d_in[2];
    const float* W1 = (const float*)d_in[3];
    const float* b1 = (const float*)d_in[4];
    const float* W2 = (const float*)d_in[5];
    const float* b2 = (const float*)d_in[6];
    float* out = (float*)d_out;

    char* ws = (char*)d_ws;
    size_t off = 0;
    auto alloc = [&](size_t bytes) {
        size_t o = off; off += (bytes + 255) & ~(size_t)255; return o;
    };
    const int ROWS = Tn * 2;            // 16384 dispatch rows
    const int RCAP = ROWS + 256;        // slack for tile overreads

    unsigned short* Wt = (unsigned short*)(ws + alloc((size_t)En * Hn * Dn * 2)); // W1t then W2t
    unsigned short* xg = (unsigned short*)(ws + alloc((size_t)RCAP * Dn * 2));
    unsigned short* hg = (unsigned short*)(ws + alloc((size_t)RCAP * Hn * 2));
    unsigned short* yv = (unsigned short*)(ws + alloc((size_t)RCAP * Dn * 2));   // bf16 y
    int*   cnt     = (int*)(ws + alloc(En * 4));
    int*   base    = (int*)(ws + alloc((En + 1) * 4));
    int*   mb      = (int*)(ws + alloc((En + 1) * 4));
    int*   tok_e   = (int*)(ws + alloc(Tn * 2 * 4));
    int*   tok_pos = (int*)(ws + alloc(Tn * 2 * 4));
    float* tok_w   = (float*)(ws + alloc(Tn * 2 * 4));
    (void)ws_size; (void)in_sizes; (void)n_in; (void)out_size;

    hipMemsetAsync(cnt, 0, En * 4, stream);

    gate_kernel<<<Tn / 16, 256, 0, stream>>>(x, Wg, bg, cnt, tok_e, tok_pos, tok_w);
    scan_kernel<<<1, 64, 0, stream>>>(cnt, base, mb);
    gather_kernel<<<Tn, 256, 0, stream>>>(x, tok_e, tok_pos, base, xg);

    // W1 [E][Dn][Hn] -> Wt [E][Hn][Dn] bf16
    convT_kernel<<<dim3(Hn / 64, Dn / 64, En), 512, 0, stream>>>(W1, Wt, Dn, Hn);
    // gemm1: 128x128, 4 blocks/CU -> grid 1024, grid-stride, gm-major
    gemm128_kernel<true><<<1024, 256, 0, stream>>>(
        xg, Wt, b1, hg, cnt, base, mb);

    // W2 [E][Hn][Dn] -> Wt [E][Dn][Hn] bf16
    convT_kernel<<<dim3(Dn / 64, Hn / 64, En), 512, 0, stream>>>(W2, Wt, Hn, Dn);
    // gemm2: K=4096 undivided, bf16 y out, gm-major
    gemm128_kernel<false><<<1024, 256, 0, stream>>>(
        hg, Wt, b2, yv, cnt, base, mb);

    combine_kernel<<<Tn, 256, 0, stream>>>(yv, tok_e, tok_pos, base, tok_w, out);
}

// Round 14
// 695.168 us; speedup vs baseline: 2.4008x; 1.0244x over previous
//
#include <hip/hip_runtime.h>
#include <hip/hip_bf16.h>
#include <stdint.h>

// MoE: T=8192, D=1024, H=4096, E=16, top-2. Sparse dispatch + bf16 MFMA GEMMs.
// GEMM core: 128x128 tiles, 4 waves, BK=32 ring-2 (32 KB), 4 blocks/CU,
// packed 128B-row LDS + XOR involution (0 conflicts), counted vmcnt(4).
// THIS ROUND: hierarchical L2 tile-blocking. gemm1: 8gm x 8nt groups
// (A 2MB + B 2MB = 4MB per-XCD L2) -> B re-reads become L2 hits.
// gemm2: K-split 2 (bf16 partials, R8-proven) + 4gm x 4knt kh-uniform groups.

#define Tn 8192
#define Dn 1024
#define Hn 4096
#define En 16

typedef __attribute__((ext_vector_type(8))) short bf16x8;
typedef __attribute__((ext_vector_type(4))) float f32x4;

__device__ __forceinline__ unsigned short f2bf(float f) {
    union { __hip_bfloat16 h; unsigned short u; } cv;
    cv.h = __float2bfloat16(f);
    return cv.u;
}
__device__ __forceinline__ float bf2f(unsigned short u) {
    union { unsigned int i; float f; } cv;
    cv.i = ((unsigned int)u) << 16;
    return cv.f;
}

__device__ __forceinline__ void gload_lds16(const void* gptr, void* lptr) {
    __builtin_amdgcn_global_load_lds(
        (const __attribute__((address_space(1))) uint32_t*)gptr,
        (__attribute__((address_space(3))) uint32_t*)lptr, 16, 0, 0);
}

// bijective XCD-chunked swizzle (m204)
__device__ __forceinline__ int swz_tile(int v, int total) {
    int q = total >> 3, r = total & 7;
    int x = v & 7, k = v >> 3;
    int b = (x < r) ? x * (q + 1) : r * (q + 1) + (x - r) * q;
    return b + k;
}

// e = #{i in [1,En) : mb[i] <= gm}
__device__ __forceinline__ int find_e(const int* __restrict__ mb, int gm) {
    int e = 0;
#pragma unroll
    for (int i = 1; i < En; i++) e += (mb[i] <= gm) ? 1 : 0;
    return e;
}

__device__ __forceinline__ void waitvm4()  { asm volatile("s_waitcnt vmcnt(4)" ::: "memory"); }
__device__ __forceinline__ void waitvm0()  { asm volatile("s_waitcnt vmcnt(0)" ::: "memory"); }
__device__ __forceinline__ void barrier_raw() { asm volatile("s_barrier" ::: "memory"); }

__device__ __forceinline__ bool better(float va, int ia, float vb, int ib) {
    return (va > vb) || (va == vb && ia < ib);
}

// ---------------- gate: 16 tokens/block, Wg in LDS, shuffle top-2 -----------
__global__ __launch_bounds__(256) void gate_kernel(
    const float* __restrict__ x, const float* __restrict__ Wg,
    const float* __restrict__ bg,
    int* cnt, int* tok_e, int* tok_pos, float* tok_w)
{
    __shared__ float wgt[16 * 1028];
    int tid = threadIdx.x;
    int t0 = blockIdx.x * 16;

#pragma unroll
    for (int i = 0; i < 64; i++) {
        int idx = i * 256 + tid;
        int k = idx >> 4, e = idx & 15;
        wgt[e * 1028 + k] = Wg[idx];
    }
    __syncthreads();

    int tok = tid >> 4, e = tid & 15;
    const float4* xr = reinterpret_cast<const float4*>(x + (size_t)(t0 + tok) * Dn);
    const float4* wr = reinterpret_cast<const float4*>(&wgt[e * 1028]);
    float acc = 0.f;
#pragma unroll 8
    for (int q = 0; q < 256; q++) {
        float4 xv = xr[q], wv = wr[q];
        acc += xv.x * wv.x + xv.y * wv.y + xv.z * wv.z + xv.w * wv.w;
    }
    acc += bg[e];

    float v0 = acc, v1 = -1e30f;
    int i0 = e, i1 = -1;
#pragma unroll
    for (int m = 1; m < 16; m <<= 1) {
        float ov0 = __shfl_xor(v0, m, 16); int oi0 = __shfl_xor(i0, m, 16);
        float ov1 = __shfl_xor(v1, m, 16); int oi1 = __shfl_xor(i1, m, 16);
        if (better(ov0, oi0, v0, i0)) {
            if (better(v0, i0, ov1, oi1)) { v1 = v0; i1 = i0; }
            else                          { v1 = ov1; i1 = oi1; }
            v0 = ov0; i0 = oi0;
        } else if (better(ov0, oi0, v1, i1)) {
            v1 = ov0; i1 = oi0;
        }
    }
    if (e == 0) {
        float ex = __expf(v1 - v0);
        float w0 = 1.f / (1.f + ex);
        float w1 = ex / (1.f + ex);
        int p0 = atomicAdd(&cnt[i0], 1);
        int p1 = atomicAdd(&cnt[i1], 1);
        int t = t0 + tok;
        tok_e[t * 2 + 0] = i0; tok_e[t * 2 + 1] = i1;
        tok_pos[t * 2 + 0] = p0; tok_pos[t * 2 + 1] = p1;
        tok_w[t * 2 + 0] = w0; tok_w[t * 2 + 1] = w1;
    }
}

// ---------------- scan: row bases + cumulative 128-row mtiles ---------------
__global__ void scan_kernel(const int* cnt, int* base, int* mb)
{
    if (threadIdx.x == 0 && blockIdx.x == 0) {
        int b = 0, m = 0;
        for (int e = 0; e < En; e++) {
            base[e] = b; mb[e] = m;
            b += cnt[e];
            m += (cnt[e] + 127) >> 7;
        }
        base[En] = b; mb[En] = m;
    }
}

// ---------------- gather ----------------------------------------------------
__global__ __launch_bounds__(256) void gather_kernel(
    const float* __restrict__ x, const int* tok_e, const int* tok_pos,
    const int* base, unsigned short* xg)
{
    int t = blockIdx.x; int tid = threadIdx.x;
    int e0 = tok_e[2 * t], e1 = tok_e[2 * t + 1];
    int r0 = base[e0] + tok_pos[2 * t];
    int r1 = base[e1] + tok_pos[2 * t + 1];
    float4 v = *reinterpret_cast<const float4*>(x + (size_t)t * Dn + tid * 4);
    ushort4 u;
    u.x = f2bf(v.x); u.y = f2bf(v.y); u.z = f2bf(v.z); u.w = f2bf(v.w);
    *reinterpret_cast<ushort4*>(xg + (size_t)r0 * Dn + tid * 4) = u;
    *reinterpret_cast<ushort4*>(xg + (size_t)r1 * Dn + tid * 4) = u;
}

// ---------------- convT: [R][C] f32 -> [C][R] bf16, 64x64 tiles -------------
__global__ __launch_bounds__(512) void convT_kernel(
    const float* __restrict__ src, unsigned short* __restrict__ dst, int R, int C)
{
    int e = blockIdx.z;
    const float* s = src + (size_t)e * R * C;
    unsigned short* d = dst + (size_t)e * R * C;
    __shared__ float tile[64][65];
    int r0 = blockIdx.y * 64, c0 = blockIdx.x * 64;
    int tr = threadIdx.x >> 4;
    int tc4 = (threadIdx.x & 15) * 4;
    float4 v0 = *reinterpret_cast<const float4*>(s + (size_t)(r0 + tr) * C + c0 + tc4);
    float4 v1 = *reinterpret_cast<const float4*>(s + (size_t)(r0 + tr + 32) * C + c0 + tc4);
    tile[tr][tc4 + 0] = v0.x; tile[tr][tc4 + 1] = v0.y;
    tile[tr][tc4 + 2] = v0.z; tile[tr][tc4 + 3] = v0.w;
    tile[tr + 32][tc4 + 0] = v1.x; tile[tr + 32][tc4 + 1] = v1.y;
    tile[tr + 32][tc4 + 2] = v1.z; tile[tr + 32][tc4 + 3] = v1.w;
    __syncthreads();
    ushort4 u0, u1;
    u0.x = f2bf(tile[tc4 + 0][tr]);      u1.x = f2bf(tile[tc4 + 0][tr + 32]);
    u0.y = f2bf(tile[tc4 + 1][tr]);      u1.y = f2bf(tile[tc4 + 1][tr + 32]);
    u0.z = f2bf(tile[tc4 + 2][tr]);      u1.z = f2bf(tile[tc4 + 2][tr + 32]);
    u0.w = f2bf(tile[tc4 + 3][tr]);      u1.w = f2bf(tile[tc4 + 3][tr + 32]);
    *reinterpret_cast<ushort4*>(d + (size_t)(c0 + tr) * R + r0 + tc4) = u0;
    *reinterpret_cast<ushort4*>(d + (size_t)(c0 + tr + 32) * R + r0 + tc4) = u1;
}

// ---------------- 128x128 GEMM, 4 waves, BK=32 ring-2, 4 blocks/CU ----------
// Hierarchical L2-blocked tile order within the XCD chunk:
//   G1: groups of 8gm x 8nt (64 tiles): A 2MB + B 2MB = 4MB L2 working set.
//   G2: K-split 2 (KLEN=2048, bf16 partials) + groups of 4gm x 4knt
//       (kh-uniform): A 1MB + B 2MB.
template<bool G1>
__global__ __launch_bounds__(256, 4) void gemm128_kernel(
    const unsigned short* __restrict__ Ag, const unsigned short* __restrict__ Bg,
    const float* __restrict__ bias, unsigned short* __restrict__ outb,
    size_t ystride,
    const int* __restrict__ cnt, const int* __restrict__ base,
    const int* __restrict__ mb)
{
    constexpr int KDIM = G1 ? Dn : Hn;       // row stride of A and B
    constexpr int KLEN = G1 ? Dn : (Hn / 2); // K per pass
    constexpr int NOUT = G1 ? Hn : Dn;
    constexpr int NT = KLEN / 32;            // K sub-tiles (32 or 64)
    __shared__ unsigned short ldsA[2][64 * 64];   // 2 x 8 KB
    __shared__ unsigned short ldsB[2][64 * 64];   // 2 x 8 KB  (32 KB total)

    int totalgm = mb[En];
    // padded tile counts for hierarchical grouping
    int ptotal;
    if constexpr (G1) ptotal = (((totalgm + 7) >> 3) << 8);   // G8*8 gm * 32 nt
    else              ptotal = (((totalgm + 3) >> 2) << 6);   // G4*4 gm * 16 knt

    int tid = threadIdx.x;
    int lane = tid & 63;
    int w = tid >> 6;
    int wm = (w >> 1) * 64, wn = (w & 1) * 64;
    int lr16 = lane & 15, lk = lane >> 4;
    int lj = lk * 4;

    // staging chunks: c = tid + i*256 (i=0,1) -> ldsrow = c>>3, ch = c&7;
    // involution ch' = ch ^ (ldsrow&7); global row = 2*ldsrow + (ch'>>2),
    // k-chunk = ch'&3.
    int lrow0 = tid >> 3;            // 0..31
    int lrow1 = (tid + 256) >> 3;    // 32..63
    int ch0 = (tid & 7) ^ (lrow0 & 7);
    int ch1 = (tid & 7) ^ (lrow1 & 7);
    int grow0 = lrow0 * 2 + (ch0 >> 2), kc0 = ch0 & 3;
    int grow1 = lrow1 * 2 + (ch1 >> 2), kc1 = ch1 & 3;

    // fragment LDS offsets (elems, slot-relative), same involution
    int aoff[4], boff[4];
#pragma unroll
    for (int m = 0; m < 4; m++) {
        int row = wm + m * 16 + lr16;
        int lr = row >> 1;
        aoff[m] = lr * 64 + (((((row & 1) << 2) | lk) ^ (lr & 7)) << 3);
    }
#pragma unroll
    for (int n = 0; n < 4; n++) {
        int row = wn + n * 16 + lr16;
        int lr = row >> 1;
        boff[n] = lr * 64 + (((((row & 1) << 2) | lk) ^ (lr & 7)) << 3);
    }

    for (int v = blockIdx.x; v < ptotal; v += gridDim.x) {
        int tile = swz_tile(v, ptotal);
        int gm, nt, kh;
        if constexpr (G1) {
            int group = tile >> 6, within = tile & 63;   // 8gm x 8nt
            int gmb = group >> 2, ntb = group & 3;       // 4 nt-blocks
            gm = (gmb << 3) + (within >> 3);
            nt = (ntb << 3) + (within & 7);
            kh = 0;
        } else {
            int group = tile >> 4, within = tile & 15;   // 4gm x 4knt
            int gmb = group >> 2, knb = group & 3;       // 4 knt-blocks
            gm = (gmb << 2) + (within >> 2);
            int knt = (knb << 2) + (within & 3);         // kh-uniform per group
            kh = knt >> 3; nt = knt & 7;
        }
        if (gm >= totalgm) continue;                     // block-uniform skip

        int e = find_e(mb, gm);
        int mtile = gm - mb[e];
        int M_e = cnt[e];
        int m0 = mtile * 128, n0 = nt * 128;
        int kbase = kh * KLEN;
        int rowbase0 = base[e] + m0;
        const unsigned short* Ab = Ag + (size_t)rowbase0 * KDIM + kbase;
        const unsigned short* Bb = Bg + ((size_t)e * NOUT + n0) * KDIM + kbase;

        const unsigned short* aS0 = Ab + (size_t)grow0 * KDIM + kc0 * 8;
        const unsigned short* aS1 = Ab + (size_t)grow1 * KDIM + kc1 * 8;
        const unsigned short* bS0 = Bb + (size_t)grow0 * KDIM + kc0 * 8;
        const unsigned short* bS1 = Bb + (size_t)grow1 * KDIM + kc1 * 8;

        f32x4 acc[4][4];
#pragma unroll
        for (int m = 0; m < 4; m++)
#pragma unroll
            for (int n = 0; n < 4; n++) acc[m][n] = (f32x4){0.f, 0.f, 0.f, 0.f};

        auto stage = [&](int t) {
            char* sa = (char*)ldsA[t & 1];
            char* sb = (char*)ldsB[t & 1];
            int k0 = t * 32;
            gload_lds16(aS0 + k0, sa + tid * 16);
            gload_lds16(aS1 + k0, sa + (tid + 256) * 16);
            gload_lds16(bS0 + k0, sb + tid * 16);
            gload_lds16(bS1 + k0, sb + (tid + 256) * 16);
        };

        stage(0);
        stage(1);

        for (int t = 0; t < NT; ++t) {
            if (t + 1 < NT) waitvm4();   // subtile t landed; t+1 stays in flight
            else            waitvm0();
            barrier_raw();
            const unsigned short* sa = ldsA[t & 1];
            const unsigned short* sb = ldsB[t & 1];
            bf16x8 a[4], b[4];
#pragma unroll
            for (int n = 0; n < 4; n++) b[n] = *(const bf16x8*)(sb + boff[n]);
#pragma unroll
            for (int m = 0; m < 4; m++) a[m] = *(const bf16x8*)(sa + aoff[m]);
            __builtin_amdgcn_s_setprio(1);
#pragma unroll
            for (int m = 0; m < 4; m++)
#pragma unroll
                for (int n = 0; n < 4; n++)
                    acc[m][n] = __builtin_amdgcn_mfma_f32_16x16x32_bf16(b[n], a[m], acc[m][n], 0, 0, 0);
            __builtin_amdgcn_s_setprio(0);
            barrier_raw();               // all waves finished reading slot t&1
            if (t + 2 < NT) stage(t + 2);
        }

        // ---- epilogue: lane holds row (lr16) x 4 consecutive cols ----
        bool addb = G1 || (kh == 0);
        const float* be = bias + (size_t)e * NOUT;
        unsigned short* ob = outb + (G1 ? 0 : (size_t)kh * ystride);
#pragma unroll
        for (int m = 0; m < 4; m++) {
            int rt = wm + m * 16 + lr16;
            if (m0 + rt < M_e) {
                size_t rowoff = (size_t)(rowbase0 + rt) * NOUT;
#pragma unroll
                for (int n = 0; n < 4; n++) {
                    int col0e = n0 + wn + n * 16 + lj;
                    float4 bs = addb ? *reinterpret_cast<const float4*>(be + col0e)
                                     : (float4){0.f, 0.f, 0.f, 0.f};
                    float v0 = acc[m][n][0] + bs.x;
                    float v1 = acc[m][n][1] + bs.y;
                    float v2 = acc[m][n][2] + bs.z;
                    float v3 = acc[m][n][3] + bs.w;
                    ushort4 u;
                    if constexpr (G1) {
                        u.x = f2bf(fmaxf(v0, 0.f));
                        u.y = f2bf(fmaxf(v1, 0.f));
                        u.z = f2bf(fmaxf(v2, 0.f));
                        u.w = f2bf(fmaxf(v3, 0.f));
                    } else {
                        u.x = f2bf(v0); u.y = f2bf(v1);
                        u.z = f2bf(v2); u.w = f2bf(v3);
                    }
                    *reinterpret_cast<ushort4*>(ob + rowoff + col0e) = u;
                }
            }
        }
    }
}

// ---------------- combine: out[t] = w0*(y0+y1)[r0] + w1*(y0+y1)[r1] ---------
__global__ __launch_bounds__(256) void combine_kernel(
    const unsigned short* __restrict__ y, size_t ystride,
    const int* __restrict__ tok_e, const int* __restrict__ tok_pos,
    const int* __restrict__ base, const float* __restrict__ tok_w,
    float* __restrict__ out)
{
    int t = blockIdx.x, tid = threadIdx.x;
    int e0 = tok_e[2 * t], e1 = tok_e[2 * t + 1];
    int r0 = base[e0] + tok_pos[2 * t];
    int r1 = base[e1] + tok_pos[2 * t + 1];
    float w0 = tok_w[2 * t], w1 = tok_w[2 * t + 1];
    const unsigned short* y1 = y + ystride;
    ushort4 a0 = *reinterpret_cast<const ushort4*>(y  + (size_t)r0 * Dn + tid * 4);
    ushort4 a1 = *reinterpret_cast<const ushort4*>(y1 + (size_t)r0 * Dn + tid * 4);
    ushort4 b0 = *reinterpret_cast<const ushort4*>(y  + (size_t)r1 * Dn + tid * 4);
    ushort4 b1 = *reinterpret_cast<const ushort4*>(y1 + (size_t)r1 * Dn + tid * 4);
    float4 o;
    o.x = w0 * (bf2f(a0.x) + bf2f(a1.x)) + w1 * (bf2f(b0.x) + bf2f(b1.x));
    o.y = w0 * (bf2f(a0.y) + bf2f(a1.y)) + w1 * (bf2f(b0.y) + bf2f(b1.y));
    o.z = w0 * (bf2f(a0.z) + bf2f(a1.z)) + w1 * (bf2f(b0.z) + bf2f(b1.z));
    o.w = w0 * (bf2f(a0.w) + bf2f(a1.w)) + w1 * (bf2f(b0.w) + bf2f(b1.w));
    *reinterpret_cast<float4*>(out + (size_t)t * Dn + tid * 4) = o;
}

// ---------------- launch ----------------------------------------------------
extern "C" void kernel_launch(void* const* d_in, const int* in_sizes, int n_in,
                              void* d_out, int out_size, void* d_ws, size_t ws_size,
                              hipStream_t stream)
{
    const float* x  = (const float*)d_in[0];
    const float* Wg = (const float*)d_in[1];
    const float* bg = (const float*)d_in[2];
    const float* W1 = (const float*)d_in[3];
    const float* b1 = (const float*)d_in[4];
    const float* W2 = (const float*)d_in[5];
    const float* b2 = (const float*)d_in[6];
    float* out = (float*)d_out;

    char* ws = (char*)d_ws;
    size_t off = 0;
    auto alloc = [&](size_t bytes) {
        size_t o = off; off += (bytes + 255) & ~(size_t)255; return o;
    };
    const int ROWS = Tn * 2;            // 16384 dispatch rows
    const int RCAP = ROWS + 256;        // slack for tile overreads
    const size_t YSTR = (size_t)RCAP * Dn;

    unsigned short* Wt = (unsigned short*)(ws + alloc((size_t)En * Hn * Dn * 2)); // W1t then W2t
    unsigned short* xg = (unsigned short*)(ws + alloc((size_t)RCAP * Dn * 2));
    unsigned short* hg = (unsigned short*)(ws + alloc((size_t)RCAP * Hn * 2));
    unsigned short* yv = (unsigned short*)(ws + alloc(2 * YSTR * 2));   // y0 | y1 bf16
    int*   cnt     = (int*)(ws + alloc(En * 4));
    int*   base    = (int*)(ws + alloc((En + 1) * 4));
    int*   mb      = (int*)(ws + alloc((En + 1) * 4));
    int*   tok_e   = (int*)(ws + alloc(Tn * 2 * 4));
    int*   tok_pos = (int*)(ws + alloc(Tn * 2 * 4));
    float* tok_w   = (float*)(ws + alloc(Tn * 2 * 4));
    (void)ws_size; (void)in_sizes; (void)n_in; (void)out_size;

    hipMemsetAsync(cnt, 0, En * 4, stream);

    gate_kernel<<<Tn / 16, 256, 0, stream>>>(x, Wg, bg, cnt, tok_e, tok_pos, tok_w);
    scan_kernel<<<1, 64, 0, stream>>>(cnt, base, mb);
    gather_kernel<<<Tn, 256, 0, stream>>>(x, tok_e, tok_pos, base, xg);

    // W1 [E][Dn][Hn] -> Wt [E][Hn][Dn] bf16
    convT_kernel<<<dim3(Hn / 64, Dn / 64, En), 512, 0, stream>>>(W1, Wt, Dn, Hn);
    // gemm1: 128x128, 4 blocks/CU, hierarchical 8gm x 8nt groups
    gemm128_kernel<true><<<1024, 256, 0, stream>>>(
        xg, Wt, b1, hg, 0, cnt, base, mb);

    // W2 [E][Hn][Dn] -> Wt [E][Dn][Hn] bf16
    convT_kernel<<<dim3(Dn / 64, Hn / 64, En), 512, 0, stream>>>(W2, Wt, Hn, Dn);
    // gemm2: K-split 2, bf16 partials, hierarchical 4gm x 4knt groups
    gemm128_kernel<false><<<1024, 256, 0, stream>>>(
        hg, Wt, b2, yv, YSTR, cnt, base, mb);

    combine_kernel<<<Tn, 256, 0, stream>>>(yv, YSTR, tok_e, tok_pos, base, tok_w, out);
}